// Round 12
// baseline (393.544 us; speedup 1.0000x reference)
//
#include <hip/hip_runtime.h>
#include <cstdint>
#include <cstddef>

typedef __attribute__((ext_vector_type(4))) float f32x4;
typedef __attribute__((ext_vector_type(8))) _Float16 half8v;
typedef __attribute__((ext_vector_type(2))) _Float16 half2v;

static inline int cdiv(int a, int b){ return (a + b - 1) / b; }

#define BSH 9              // bucket shift: 512 nodes per bucket
#define CH 8192            // edges per scatter block
#define HCH 8192           // edges per histogram block

// ---------------- K1: weight-convert (blocks 0..223) || bucket histogram (rest) ----------------

__global__ __launch_bounds__(256) void wcvt_bhist_kernel(const float* __restrict__ W1, _Float16* __restrict__ W1t,
                                                         const float* __restrict__ W2, _Float16* __restrict__ W2t,
                                                         const float* __restrict__ W3, _Float16* __restrict__ W3t,
                                                         const int* __restrict__ dst, int* __restrict__ bktcnt,
                                                         int E, int NBK){
  __shared__ int hist[1024];
  int b = blockIdx.x, t = threadIdx.x;
  if (b < 224){
    int i = b * 256 + t;
    if (b < 128){
      int k = i / 128, n = i & 127;
      W1t[(size_t)n * 256 + k] = (_Float16)W1[i];
    } else if (b < 192){
      int j = i - 128 * 256;
      int k = j / 128, n = j & 127;
      W2t[(size_t)n * 128 + k] = (_Float16)W2[j];
    } else {
      int j = i - 192 * 256;
      int k = j / 64, n = j & 63;
      W3t[(size_t)n * 128 + k] = (_Float16)W3[j];
    }
    return;
  }
  int cb = b - 224;
  for (int i = t; i < NBK; i += 256) hist[i] = 0;
  __syncthreads();
  int e0 = cb * HCH;
  int e1 = e0 + HCH; if (e1 > E) e1 = E;
  for (int i = e0 + t; i < e1; i += 256){
    int d = __builtin_nontemporal_load(dst + i);
    atomicAdd(&hist[d >> BSH], 1);
  }
  __syncthreads();
  for (int i = t; i < NBK; i += 256){
    int h = hist[i];
    if (h) atomicAdd(&bktcnt[i], h);
  }
}

// ---------------- K2: one-block scan over NBK bucket counts -> bbase, bcur ----------------

__global__ __launch_bounds__(256) void bucket_scan_kernel(const int* __restrict__ bktcnt, int* __restrict__ bbase,
                                                          int* __restrict__ bcur, int NBK, int E){
  __shared__ int sdata[256];
  int t = threadIdx.x;
  int c = (t < NBK) ? bktcnt[t] : 0;
  sdata[t] = c;
  __syncthreads();
  for (int off = 1; off < 256; off <<= 1){
    int v = (t >= off) ? sdata[t - off] : 0;
    __syncthreads();
    sdata[t] += v;
    __syncthreads();
  }
  if (t < NBK){
    int ex = sdata[t] - c;
    bbase[t] = ex;
    bcur[t] = ex;
  }
  if (t == 0) bbase[NBK] = E;
}

// ---------------- K3: block-histogram bucket scatter ----------------

__global__ __launch_bounds__(256) void bucket_scatter_kernel(const int* __restrict__ src, const int* __restrict__ dst,
                                                             int* __restrict__ bcur, unsigned* __restrict__ tmp,
                                                             int E, int NBK){
  __shared__ int hist[1024];
  __shared__ int hbase[1024];
  __shared__ unsigned pk[CH];
  __shared__ unsigned short bkt[CH];
  int t = threadIdx.x;
  int e0 = blockIdx.x * CH;
  int e1 = e0 + CH; if (e1 > E) e1 = E;
  int nloc = e1 - e0;
  for (int i = t; i < NBK; i += 256) hist[i] = 0;
  __syncthreads();
  for (int i = t; i < nloc; i += 256){
    int d = __builtin_nontemporal_load(dst + e0 + i);
    int s = __builtin_nontemporal_load(src + e0 + i);
    int b = d >> BSH;
    pk[i]  = ((unsigned)s << BSH) | (unsigned)(d & ((1 << BSH) - 1));
    bkt[i] = (unsigned short)b;
    atomicAdd(&hist[b], 1);
  }
  __syncthreads();
  for (int i = t; i < NBK; i += 256){
    int h = hist[i];
    hbase[i] = h ? atomicAdd(&bcur[i], h) : 0;
    hist[i] = 0;                         // reuse as intra-block cursor
  }
  __syncthreads();
  for (int i = t; i < nloc; i += 256){
    int b = bkt[i];
    int pos = atomicAdd(&hist[b], 1);
    tmp[hbase[b] + pos] = pk[i];
  }
}

// ---------------- K4: per-bucket build: node histogram -> dinv + row_off (LDS scan) -> cursor sort ----------------

__global__ __launch_bounds__(256) void bucket_build_kernel(const unsigned* __restrict__ tmp, const int* __restrict__ bbase,
                                                           int* __restrict__ row_off, float* __restrict__ dinv,
                                                           int* __restrict__ csr_src, int N, int E, int NBK){
  __shared__ int hist[512];
  __shared__ int sdata[256];
  __shared__ int lofs[512];
  int g = blockIdx.x;
  int base = g << BSH;
  int nloc = N - base; if (nloc > 512) nloc = 512;
  int t = threadIdx.x;
  int rs = bbase[g], re = bbase[g + 1];
  hist[t] = 0; hist[t + 256] = 0;
  __syncthreads();
  for (int i = rs + t; i < re; i += 256)
    atomicAdd(&hist[tmp[i] & 511], 1);
  __syncthreads();
  int h0 = hist[2 * t], h1 = hist[2 * t + 1];
  int pairsum = h0 + h1;
  sdata[t] = pairsum;
  __syncthreads();
  for (int off = 1; off < 256; off <<= 1){
    int v = (t >= off) ? sdata[t - off] : 0;
    __syncthreads();
    sdata[t] += v;
    __syncthreads();
  }
  int ex = sdata[t] - pairsum;
  lofs[2 * t] = ex;
  lofs[2 * t + 1] = ex + h0;
  __syncthreads();
  for (int j = t; j < nloc; j += 256){
    dinv[base + j] = rsqrtf((float)hist[j] + 1.0f);
    row_off[base + j] = rs + lofs[j];
  }
  if (g == NBK - 1 && t == 0) row_off[N] = E;
  __syncthreads();
  for (int j = t; j < 512; j += 256) hist[j] = rs + lofs[j];   // reuse as cursors
  __syncthreads();
  for (int i = rs + t; i < re; i += 256){
    unsigned v = tmp[i];
    int slot = atomicAdd(&hist[v & 511], 1);
    csr_src[slot] = (int)(v >> BSH);
  }
}

// ---------------- pipelined MFMA GEMM (layer 1): C16[row] = fp16(dscale[row] * (A @ Bt^T)[row]) ----------------

template<int BN, bool A32IN>
__global__ __launch_bounds__(256) void mgemm_kernel(const void* __restrict__ Ain, const _Float16* __restrict__ Bt,
                                                    _Float16* __restrict__ C16, const float* __restrict__ dscale,
                                                    int M, int K){
  constexpr int BM = 128, LD = 40;
  constexpr int MF = (BN == 128) ? 4 : 2;
  constexpr int NBC = (BN * 4) / 256;
  __shared__ _Float16 As[BM * LD];
  __shared__ _Float16 Bs[BN * LD];
  const float*    A32 = (const float*)Ain;
  const _Float16* A16 = (const _Float16*)Ain;
  int t = threadIdx.x;
  int w = t >> 6, l = t & 63;
  int m0 = blockIdx.x * BM;
  int wm = (BN == 128) ? (w >> 1) * 64 : w * 32;
  int wn = (BN == 128) ? (w & 1) * 64 : 0;
  int lr = l & 15;
  int kg = (l >> 4) * 8;

  int arow = t >> 2, ac = t & 3;
  int ag0 = m0 + arow, ag1 = m0 + arow + 64;

  f32x4 acc[MF][4];
  #pragma unroll
  for (int i = 0; i < MF; i++)
    #pragma unroll
    for (int j = 0; j < 4; j++){
      f32x4 z = {0.f, 0.f, 0.f, 0.f};
      acc[i][j] = z;
    }

  float4 ar0[2][2];
  half8v ar16[2];
  half8v br[NBC];

  auto loadA = [&](int k0){
    if (A32IN){
      #pragma unroll
      for (int j = 0; j < 2; j++){
        int gr = (j == 0) ? ag0 : ag1;
        if (gr < M){
          const float* ap = A32 + (size_t)gr * K + k0 + ac * 8;
          ar0[j][0] = *reinterpret_cast<const float4*>(ap);
          ar0[j][1] = *reinterpret_cast<const float4*>(ap + 4);
        } else {
          ar0[j][0] = make_float4(0.f, 0.f, 0.f, 0.f);
          ar0[j][1] = make_float4(0.f, 0.f, 0.f, 0.f);
        }
      }
    } else {
      #pragma unroll
      for (int j = 0; j < 2; j++){
        int gr = (j == 0) ? ag0 : ag1;
        if (gr < M){
          ar16[j] = *reinterpret_cast<const half8v*>(A16 + (size_t)gr * K + k0 + ac * 8);
        } else {
          half8v z = {(_Float16)0, (_Float16)0, (_Float16)0, (_Float16)0,
                      (_Float16)0, (_Float16)0, (_Float16)0, (_Float16)0};
          ar16[j] = z;
        }
      }
    }
  };
  auto loadB = [&](int k0){
    #pragma unroll
    for (int j = 0; j < NBC; j++){
      int i = t + j * 256;
      int row = i >> 2, c = i & 3;
      br[j] = *reinterpret_cast<const half8v*>(Bt + (size_t)row * K + k0 + c * 8);
    }
  };
  auto storeLDS = [&](){
    #pragma unroll
    for (int j = 0; j < 2; j++){
      int row = arow + j * 64;
      half8v hv;
      if (A32IN){
        hv[0] = (_Float16)ar0[j][0].x; hv[1] = (_Float16)ar0[j][0].y;
        hv[2] = (_Float16)ar0[j][0].z; hv[3] = (_Float16)ar0[j][0].w;
        hv[4] = (_Float16)ar0[j][1].x; hv[5] = (_Float16)ar0[j][1].y;
        hv[6] = (_Float16)ar0[j][1].z; hv[7] = (_Float16)ar0[j][1].w;
      } else {
        hv = ar16[j];
      }
      *reinterpret_cast<half8v*>(&As[row * LD + ac * 8]) = hv;
    }
    #pragma unroll
    for (int j = 0; j < NBC; j++){
      int i = t + j * 256;
      int row = i >> 2, c = i & 3;
      *reinterpret_cast<half8v*>(&Bs[row * LD + c * 8]) = br[j];
    }
  };

  loadA(0); loadB(0);
  for (int k0 = 0; k0 < K; k0 += 32){
    storeLDS();
    __syncthreads();
    if (k0 + 32 < K){ loadA(k0 + 32); loadB(k0 + 32); }
    half8v af[MF];
    #pragma unroll
    for (int mf = 0; mf < MF; mf++)
      af[mf] = *reinterpret_cast<const half8v*>(&As[(wm + mf * 16 + lr) * LD + kg]);
    #pragma unroll
    for (int nf = 0; nf < 4; nf++){
      half8v bf = *reinterpret_cast<const half8v*>(&Bs[(wn + nf * 16 + lr) * LD + kg]);
      #pragma unroll
      for (int mf = 0; mf < MF; mf++)
        acc[mf][nf] = __builtin_amdgcn_mfma_f32_16x16x32_f16(af[mf], bf, acc[mf][nf], 0, 0, 0);
    }
    __syncthreads();
  }
  #pragma unroll
  for (int mf = 0; mf < MF; mf++){
    #pragma unroll
    for (int r = 0; r < 4; r++){
      int row = m0 + wm + mf * 16 + (l >> 4) * 4 + r;
      if (row < M){
        float sc = dscale[row];
        #pragma unroll
        for (int nf = 0; nf < 4; nf++)
          C16[(size_t)row * BN + wn + nf * 16 + lr] = (_Float16)(sc * acc[mf][nf][r]);
      }
    }
  }
}

// ---------------- fused agg + GEMM: g = relu(di*rowsum(h') + b); outH = dinv ⊙ (g @ Wt^T) ----------------
// Block = 128 nodes, 4 waves. Phase 1: wave w aggregates nodes base+w*32..+31 into LDS A-tile
// As[128][136] (g rows, fp16, 2-way bank aliasing = free). Phase 2: 16x16x32 MFMAs, B-fragments
// straight from L2-hot Wt (no Bs tile). KD (input dim) = 128 for both uses.
//   A frag: lane l row (l&15), k = kc*32 + 8*(l>>4)+{0..7};  B frag: col (l&15), same k
//   D: lane l reg r -> row = 4*(l>>4)+r, col = (l&15)

template<int BNO>
__global__ __launch_bounds__(256) void agg_gemm_kernel(const _Float16* __restrict__ h16, const int* __restrict__ row_off,
                                                       const int* __restrict__ csr_src, const float* __restrict__ dinv,
                                                       const float* __restrict__ bias, const _Float16* __restrict__ Wt,
                                                       _Float16* __restrict__ outH, int n){
  constexpr int ALD = 136;           // 128 + 8 pad halves; rows 272 B (16B-aligned), 2-way bank aliasing
  __shared__ _Float16 As[128 * ALD];
  int t = threadIdx.x, w = t >> 6, l = t & 63;
  int base = blockIdx.x * 128;

  // ---- phase 1: aggregate 32 nodes per wave ----
  float2 bv = *reinterpret_cast<const float2*>(bias + l * 2);
  for (int i = 0; i < 32; i++){
    int r = w * 32 + i;
    int nd = base + r;
    half2v g; g[0] = (_Float16)0; g[1] = (_Float16)0;
    if (nd < n){
      int e = row_off[nd], eend = row_off[nd + 1];
      float di = dinv[nd];
      half2v sv = *reinterpret_cast<const half2v*>(h16 + (size_t)nd * 128 + l * 2);
      float ax = (float)sv[0], ay = (float)sv[1];
      while (e < eend){
        int m = eend - e; if (m > 64) m = 64;
        int idx = (l < m) ? csr_src[e + l] : 0;
        int j = 0;
        for (; j + 16 <= m; j += 16){
          half2v v[16];
          #pragma unroll
          for (int q = 0; q < 16; q++){
            int s = __shfl(idx, j + q);
            v[q] = *reinterpret_cast<const half2v*>(h16 + (size_t)s * 128 + l * 2);
          }
          #pragma unroll
          for (int q = 0; q < 16; q++){ ax += (float)v[q][0]; ay += (float)v[q][1]; }
        }
        for (; j + 4 <= m; j += 4){
          half2v v[4];
          #pragma unroll
          for (int q = 0; q < 4; q++){
            int s = __shfl(idx, j + q);
            v[q] = *reinterpret_cast<const half2v*>(h16 + (size_t)s * 128 + l * 2);
          }
          #pragma unroll
          for (int q = 0; q < 4; q++){ ax += (float)v[q][0]; ay += (float)v[q][1]; }
        }
        for (; j < m; j++){
          int s = __shfl(idx, j);
          half2v v = *reinterpret_cast<const half2v*>(h16 + (size_t)s * 128 + l * 2);
          ax += (float)v[0]; ay += (float)v[1];
        }
        e += m;
      }
      g[0] = (_Float16)fmaxf(fmaf(di, ax, bv.x), 0.f);
      g[1] = (_Float16)fmaxf(fmaf(di, ay, bv.y), 0.f);
    }
    *reinterpret_cast<half2v*>(&As[r * ALD + l * 2]) = g;
  }
  __syncthreads();

  // ---- phase 2: G[128x128] @ Wt^T -> scale by dinv -> outH ----
  constexpr int MF = (BNO == 128) ? 4 : 2;
  int wm = (BNO == 128) ? (w >> 1) * 64 : w * 32;
  int wn = (BNO == 128) ? (w & 1) * 64 : 0;
  int lr = l & 15;
  int kg = (l >> 4) * 8;
  f32x4 acc[MF][4];
  #pragma unroll
  for (int i = 0; i < MF; i++)
    #pragma unroll
    for (int j = 0; j < 4; j++){
      f32x4 z = {0.f, 0.f, 0.f, 0.f};
      acc[i][j] = z;
    }
  #pragma unroll
  for (int kc = 0; kc < 4; kc++){
    half8v af[MF];
    #pragma unroll
    for (int mf = 0; mf < MF; mf++)
      af[mf] = *reinterpret_cast<const half8v*>(&As[(wm + mf * 16 + lr) * ALD + kc * 32 + kg]);
    #pragma unroll
    for (int nf = 0; nf < 4; nf++){
      half8v bf = *reinterpret_cast<const half8v*>(Wt + (size_t)(wn + nf * 16 + lr) * 128 + kc * 32 + kg);
      #pragma unroll
      for (int mf = 0; mf < MF; mf++)
        acc[mf][nf] = __builtin_amdgcn_mfma_f32_16x16x32_f16(af[mf], bf, acc[mf][nf], 0, 0, 0);
    }
  }
  #pragma unroll
  for (int mf = 0; mf < MF; mf++){
    #pragma unroll
    for (int r = 0; r < 4; r++){
      int row = base + wm + mf * 16 + (l >> 4) * 4 + r;
      if (row < n){
        float sc = dinv[row];
        #pragma unroll
        for (int nf = 0; nf < 4; nf++)
          outH[(size_t)row * BNO + wn + nf * 16 + lr] = (_Float16)(sc * acc[mf][nf][r]);
      }
    }
  }
}

// ---------------- layer-3 agg (64-dim, h' pre-scaled) with fused classifier ----------------

__global__ __launch_bounds__(256) void agg64h_cls_kernel(const _Float16* __restrict__ h16, const int* __restrict__ row_off,
                                                         const int* __restrict__ csr_src, const float* __restrict__ dinv,
                                                         const float* __restrict__ bias, const float* __restrict__ Wc,
                                                         const float* __restrict__ bc, float* __restrict__ out, int n){
  int node = blockIdx.x * 4 + (threadIdx.x >> 6);
  if (node >= n) return;
  int lane = threadIdx.x & 63;
  int e = row_off[node], eend = row_off[node + 1];
  float di = dinv[node];
  float a = (float)h16[(size_t)node * 64 + lane];
  while (e < eend){
    int m = eend - e; if (m > 64) m = 64;
    int idx = (lane < m) ? csr_src[e + lane] : 0;
    int i = 0;
    for (; i + 16 <= m; i += 16){
      _Float16 v[16];
      #pragma unroll
      for (int j = 0; j < 16; j++){
        int s = __shfl(idx, i + j);
        v[j] = h16[(size_t)s * 64 + lane];
      }
      #pragma unroll
      for (int j = 0; j < 16; j++) a += (float)v[j];
    }
    for (; i + 4 <= m; i += 4){
      _Float16 v[4];
      #pragma unroll
      for (int j = 0; j < 4; j++){
        int s = __shfl(idx, i + j);
        v[j] = h16[(size_t)s * 64 + lane];
      }
      #pragma unroll
      for (int j = 0; j < 4; j++) a += (float)v[j];
    }
    for (; i < m; i++){
      int s = __shfl(idx, i);
      a += (float)h16[(size_t)s * 64 + lane];
    }
    e += m;
  }
  float o = fmaxf(fmaf(di, a, bias[lane]), 0.f);
  float v = o * Wc[lane];
  #pragma unroll
  for (int off = 32; off > 0; off >>= 1) v += __shfl_down(v, off);
  if (lane == 0) out[node] = v + bc[0];
}

// ---------------- launch ----------------

extern "C" void kernel_launch(void* const* d_in, const int* in_sizes, int n_in,
                              void* d_out, int out_size, void* d_ws, size_t ws_size,
                              hipStream_t stream){
  const float* x  = (const float*)d_in[0];
  const int*   ei = (const int*)d_in[1];
  const float* W1 = (const float*)d_in[2];
  const float* b1 = (const float*)d_in[3];
  const float* W2 = (const float*)d_in[4];
  const float* b2 = (const float*)d_in[5];
  const float* W3 = (const float*)d_in[6];
  const float* b3 = (const float*)d_in[7];
  const float* Wc = (const float*)d_in[8];
  const float* bc = (const float*)d_in[9];
  float* out = (float*)d_out;

  int N = in_sizes[0] / 256;
  int E = in_sizes[1] / 2;
  const int* src = ei;
  const int* dst = ei + E;
  int NBK = (N + (1 << BSH) - 1) >> BSH;   // 196 for N=100000

  char* ws = (char*)d_ws;
  size_t off = 0;
  auto alloc = [&](size_t bytes) -> char* {
    char* p = ws + off;
    off += (bytes + 511) & ~(size_t)511;
    return p;
  };
  int*      bktcnt  = (int*)     alloc((size_t)NBK * 4);
  int*      bbase   = (int*)     alloc(((size_t)NBK + 1) * 4);
  int*      bcur    = (int*)     alloc((size_t)NBK * 4);
  float*    dinv    = (float*)   alloc((size_t)N * 4);
  int*      row_off = (int*)     alloc(((size_t)N + 1) * 4);
  unsigned* tmp     = (unsigned*)alloc((size_t)E * 4);
  int*      csr_src = (int*)     alloc((size_t)E * 4);
  _Float16* bufA    = (_Float16*)alloc((size_t)N * 128 * 2);  // h1' (then h3' 64-dim)
  _Float16* bufB    = (_Float16*)alloc((size_t)N * 128 * 2);  // h2'
  _Float16* W1t     = (_Float16*)alloc((size_t)256 * 128 * 2);
  _Float16* W2t     = (_Float16*)alloc((size_t)128 * 128 * 2);
  _Float16* W3t     = (_Float16*)alloc((size_t)128 * 64 * 2);

  // K1: wcvt || bucket histogram
  hipMemsetAsync(bktcnt, 0, (size_t)NBK * 4, stream);
  wcvt_bhist_kernel<<<224 + cdiv(E, HCH), 256, 0, stream>>>(W1, W1t, W2, W2t, W3, W3t, dst, bktcnt, E, NBK);
  // K2: bucket scan
  bucket_scan_kernel<<<1, 256, 0, stream>>>(bktcnt, bbase, bcur, NBK, E);
  // K3: bucket scatter
  bucket_scatter_kernel<<<cdiv(E, CH), 256, 0, stream>>>(src, dst, bcur, tmp, E, NBK);
  // K4: per-bucket build (row_off + dinv + csr_src)
  bucket_build_kernel<<<NBK, 256, 0, stream>>>(tmp, bbase, row_off, dinv, csr_src, N, E, NBK);
  // layer 1 GEMM: bufA = dinv*(x@W1) fp16
  mgemm_kernel<128, true><<<cdiv(N, 128), 256, 0, stream>>>(x, W1t, bufA, dinv, N, 256);
  // fused layer-1 agg + layer-2 GEMM: bufB = dinv*(relu-agg(bufA) @ W2)
  agg_gemm_kernel<128><<<cdiv(N, 128), 256, 0, stream>>>(bufA, row_off, csr_src, dinv, b1, W2t, bufB, N);
  // fused layer-2 agg + layer-3 GEMM: bufA = dinv*(relu-agg(bufB) @ W3)   (64-dim out)
  agg_gemm_kernel<64><<<cdiv(N, 128), 256, 0, stream>>>(bufB, row_off, csr_src, dinv, b2, W3t, bufA, N);
  // layer-3 agg + classifier
  agg64h_cls_kernel<<<cdiv(N, 4), 256, 0, stream>>>(bufA, row_off, csr_src, dinv, b3, Wc, bc, out, N);
}

// Round 13
// 310.861 us; speedup vs baseline: 1.2660x; 1.2660x over previous
//
#include <hip/hip_runtime.h>
#include <cstdint>
#include <cstddef>

typedef __attribute__((ext_vector_type(4))) float f32x4;
typedef __attribute__((ext_vector_type(8))) _Float16 half8v;
typedef __attribute__((ext_vector_type(2))) _Float16 half2v;

static inline int cdiv(int a, int b){ return (a + b - 1) / b; }

#define BSH 9              // bucket shift: 512 nodes per bucket
#define CH 8192            // edges per scatter block
#define HCH 8192           // edges per histogram block

// ---------------- K1: weight-convert (blocks 0..223) || bucket histogram (rest) ----------------

__global__ __launch_bounds__(256) void wcvt_bhist_kernel(const float* __restrict__ W1, _Float16* __restrict__ W1t,
                                                         const float* __restrict__ W2, _Float16* __restrict__ W2t,
                                                         const float* __restrict__ W3, _Float16* __restrict__ W3t,
                                                         const int* __restrict__ dst, int* __restrict__ bktcnt,
                                                         int E, int NBK){
  __shared__ int hist[1024];
  int b = blockIdx.x, t = threadIdx.x;
  if (b < 224){
    int i = b * 256 + t;
    if (b < 128){
      int k = i / 128, n = i & 127;
      W1t[(size_t)n * 256 + k] = (_Float16)W1[i];
    } else if (b < 192){
      int j = i - 128 * 256;
      int k = j / 128, n = j & 127;
      W2t[(size_t)n * 128 + k] = (_Float16)W2[j];
    } else {
      int j = i - 192 * 256;
      int k = j / 64, n = j & 63;
      W3t[(size_t)n * 128 + k] = (_Float16)W3[j];
    }
    return;
  }
  int cb = b - 224;
  for (int i = t; i < NBK; i += 256) hist[i] = 0;
  __syncthreads();
  int e0 = cb * HCH;
  int e1 = e0 + HCH; if (e1 > E) e1 = E;
  for (int i = e0 + t; i < e1; i += 256){
    int d = __builtin_nontemporal_load(dst + i);
    atomicAdd(&hist[d >> BSH], 1);
  }
  __syncthreads();
  for (int i = t; i < NBK; i += 256){
    int h = hist[i];
    if (h) atomicAdd(&bktcnt[i], h);
  }
}

// ---------------- K2: one-block scan over NBK bucket counts -> bbase, bcur ----------------

__global__ __launch_bounds__(256) void bucket_scan_kernel(const int* __restrict__ bktcnt, int* __restrict__ bbase,
                                                          int* __restrict__ bcur, int NBK, int E){
  __shared__ int sdata[256];
  int t = threadIdx.x;
  int c = (t < NBK) ? bktcnt[t] : 0;
  sdata[t] = c;
  __syncthreads();
  for (int off = 1; off < 256; off <<= 1){
    int v = (t >= off) ? sdata[t - off] : 0;
    __syncthreads();
    sdata[t] += v;
    __syncthreads();
  }
  if (t < NBK){
    int ex = sdata[t] - c;
    bbase[t] = ex;
    bcur[t] = ex;
  }
  if (t == 0) bbase[NBK] = E;
}

// ---------------- K3: block-histogram bucket scatter ----------------

__global__ __launch_bounds__(256) void bucket_scatter_kernel(const int* __restrict__ src, const int* __restrict__ dst,
                                                             int* __restrict__ bcur, unsigned* __restrict__ tmp,
                                                             int E, int NBK){
  __shared__ int hist[1024];
  __shared__ int hbase[1024];
  __shared__ unsigned pk[CH];
  __shared__ unsigned short bkt[CH];
  int t = threadIdx.x;
  int e0 = blockIdx.x * CH;
  int e1 = e0 + CH; if (e1 > E) e1 = E;
  int nloc = e1 - e0;
  for (int i = t; i < NBK; i += 256) hist[i] = 0;
  __syncthreads();
  for (int i = t; i < nloc; i += 256){
    int d = __builtin_nontemporal_load(dst + e0 + i);
    int s = __builtin_nontemporal_load(src + e0 + i);
    int b = d >> BSH;
    pk[i]  = ((unsigned)s << BSH) | (unsigned)(d & ((1 << BSH) - 1));
    bkt[i] = (unsigned short)b;
    atomicAdd(&hist[b], 1);
  }
  __syncthreads();
  for (int i = t; i < NBK; i += 256){
    int h = hist[i];
    hbase[i] = h ? atomicAdd(&bcur[i], h) : 0;
    hist[i] = 0;                         // reuse as intra-block cursor
  }
  __syncthreads();
  for (int i = t; i < nloc; i += 256){
    int b = bkt[i];
    int pos = atomicAdd(&hist[b], 1);
    tmp[hbase[b] + pos] = pk[i];
  }
}

// ---------------- K4: per-bucket build: node histogram -> dinv + row_off (LDS scan) -> cursor sort ----------------

__global__ __launch_bounds__(256) void bucket_build_kernel(const unsigned* __restrict__ tmp, const int* __restrict__ bbase,
                                                           int* __restrict__ row_off, float* __restrict__ dinv,
                                                           int* __restrict__ csr_src, int N, int E, int NBK){
  __shared__ int hist[512];
  __shared__ int sdata[256];
  __shared__ int lofs[512];
  int g = blockIdx.x;
  int base = g << BSH;
  int nloc = N - base; if (nloc > 512) nloc = 512;
  int t = threadIdx.x;
  int rs = bbase[g], re = bbase[g + 1];
  hist[t] = 0; hist[t + 256] = 0;
  __syncthreads();
  for (int i = rs + t; i < re; i += 256)
    atomicAdd(&hist[tmp[i] & 511], 1);
  __syncthreads();
  int h0 = hist[2 * t], h1 = hist[2 * t + 1];
  int pairsum = h0 + h1;
  sdata[t] = pairsum;
  __syncthreads();
  for (int off = 1; off < 256; off <<= 1){
    int v = (t >= off) ? sdata[t - off] : 0;
    __syncthreads();
    sdata[t] += v;
    __syncthreads();
  }
  int ex = sdata[t] - pairsum;
  lofs[2 * t] = ex;
  lofs[2 * t + 1] = ex + h0;
  __syncthreads();
  for (int j = t; j < nloc; j += 256){
    dinv[base + j] = rsqrtf((float)hist[j] + 1.0f);
    row_off[base + j] = rs + lofs[j];
  }
  if (g == NBK - 1 && t == 0) row_off[N] = E;
  __syncthreads();
  for (int j = t; j < 512; j += 256) hist[j] = rs + lofs[j];   // reuse as cursors
  __syncthreads();
  for (int i = rs + t; i < re; i += 256){
    unsigned v = tmp[i];
    int slot = atomicAdd(&hist[v & 511], 1);
    csr_src[slot] = (int)(v >> BSH);
  }
}

// ---------------- pipelined MFMA GEMM: C16[row] = fp16(dscale[row] * (A @ Bt^T)[row]) ----------------
// BM=128, BK=32, 4 waves, 2-stage register prefetch (next tile's loads issue before MFMAs).
//   A: lane l row (l&15), k = 8*(l>>4)+{0..7}; B: lane l col (l&15), same k
//   D: lane l reg r -> row = 4*(l>>4)+r, col = (l&15)

template<int BN, bool A32IN>
__global__ __launch_bounds__(256) void mgemm_kernel(const void* __restrict__ Ain, const _Float16* __restrict__ Bt,
                                                    _Float16* __restrict__ C16, const float* __restrict__ dscale,
                                                    int M, int K){
  constexpr int BM = 128, LD = 40;   // stride 40 halves: 16B-aligned rows, <=2-way bank aliasing
  constexpr int MF = (BN == 128) ? 4 : 2;
  constexpr int NBC = (BN * 4) / 256;   // B chunks per thread
  __shared__ _Float16 As[BM * LD];
  __shared__ _Float16 Bs[BN * LD];
  const float*    A32 = (const float*)Ain;
  const _Float16* A16 = (const _Float16*)Ain;
  int t = threadIdx.x;
  int w = t >> 6, l = t & 63;
  int m0 = blockIdx.x * BM;
  int wm = (BN == 128) ? (w >> 1) * 64 : w * 32;
  int wn = (BN == 128) ? (w & 1) * 64 : 0;
  int lr = l & 15;
  int kg = (l >> 4) * 8;

  int arow = t >> 2, ac = t & 3;         // A chunk 0: row 0..63; chunk 1: +64
  int ag0 = m0 + arow, ag1 = m0 + arow + 64;

  f32x4 acc[MF][4];
  #pragma unroll
  for (int i = 0; i < MF; i++)
    #pragma unroll
    for (int j = 0; j < 4; j++){
      f32x4 z = {0.f, 0.f, 0.f, 0.f};
      acc[i][j] = z;
    }

  float4 ar0[2][2];       // A32 path
  half8v ar16[2];         // A16 path
  half8v br[NBC];

  auto loadA = [&](int k0){
    if (A32IN){
      #pragma unroll
      for (int j = 0; j < 2; j++){
        int gr = (j == 0) ? ag0 : ag1;
        if (gr < M){
          const float* ap = A32 + (size_t)gr * K + k0 + ac * 8;
          ar0[j][0] = *reinterpret_cast<const float4*>(ap);
          ar0[j][1] = *reinterpret_cast<const float4*>(ap + 4);
        } else {
          ar0[j][0] = make_float4(0.f, 0.f, 0.f, 0.f);
          ar0[j][1] = make_float4(0.f, 0.f, 0.f, 0.f);
        }
      }
    } else {
      #pragma unroll
      for (int j = 0; j < 2; j++){
        int gr = (j == 0) ? ag0 : ag1;
        if (gr < M){
          ar16[j] = *reinterpret_cast<const half8v*>(A16 + (size_t)gr * K + k0 + ac * 8);
        } else {
          half8v z = {(_Float16)0, (_Float16)0, (_Float16)0, (_Float16)0,
                      (_Float16)0, (_Float16)0, (_Float16)0, (_Float16)0};
          ar16[j] = z;
        }
      }
    }
  };
  auto loadB = [&](int k0){
    #pragma unroll
    for (int j = 0; j < NBC; j++){
      int i = t + j * 256;
      int row = i >> 2, c = i & 3;
      br[j] = *reinterpret_cast<const half8v*>(Bt + (size_t)row * K + k0 + c * 8);
    }
  };
  auto storeLDS = [&](){
    #pragma unroll
    for (int j = 0; j < 2; j++){
      int row = arow + j * 64;
      half8v hv;
      if (A32IN){
        hv[0] = (_Float16)ar0[j][0].x; hv[1] = (_Float16)ar0[j][0].y;
        hv[2] = (_Float16)ar0[j][0].z; hv[3] = (_Float16)ar0[j][0].w;
        hv[4] = (_Float16)ar0[j][1].x; hv[5] = (_Float16)ar0[j][1].y;
        hv[6] = (_Float16)ar0[j][1].z; hv[7] = (_Float16)ar0[j][1].w;
      } else {
        hv = ar16[j];
      }
      *reinterpret_cast<half8v*>(&As[row * LD + ac * 8]) = hv;
    }
    #pragma unroll
    for (int j = 0; j < NBC; j++){
      int i = t + j * 256;
      int row = i >> 2, c = i & 3;
      *reinterpret_cast<half8v*>(&Bs[row * LD + c * 8]) = br[j];
    }
  };

  loadA(0); loadB(0);
  for (int k0 = 0; k0 < K; k0 += 32){
    storeLDS();
    __syncthreads();
    if (k0 + 32 < K){ loadA(k0 + 32); loadB(k0 + 32); }
    half8v af[MF];
    #pragma unroll
    for (int mf = 0; mf < MF; mf++)
      af[mf] = *reinterpret_cast<const half8v*>(&As[(wm + mf * 16 + lr) * LD + kg]);
    #pragma unroll
    for (int nf = 0; nf < 4; nf++){
      half8v bf = *reinterpret_cast<const half8v*>(&Bs[(wn + nf * 16 + lr) * LD + kg]);
      #pragma unroll
      for (int mf = 0; mf < MF; mf++)
        acc[mf][nf] = __builtin_amdgcn_mfma_f32_16x16x32_f16(af[mf], bf, acc[mf][nf], 0, 0, 0);
    }
    __syncthreads();
  }
  #pragma unroll
  for (int mf = 0; mf < MF; mf++){
    #pragma unroll
    for (int r = 0; r < 4; r++){
      int row = m0 + wm + mf * 16 + (l >> 4) * 4 + r;
      if (row < M){
        float sc = dscale[row];
        #pragma unroll
        for (int nf = 0; nf < 4; nf++)
          C16[(size_t)row * BN + wn + nf * 16 + lr] = (_Float16)(sc * acc[mf][nf][r]);
      }
    }
  }
}

// ---------------- aggregation: out = relu(di * (sum_{s in N(i)} h'_s + h'_i) + b) ----------------
// h' is already dinv-scaled (GEMM epilogue). One node per wave (proven-fast shape).
// csr_src streamed with nt loads: keeps the once-read 6.4MB index stream out of L2,
// leaving more of the 32MB aggregate L2 for the 25.6MB h working set.

__global__ __launch_bounds__(256) void agg128h_kernel(const _Float16* __restrict__ h16, const int* __restrict__ row_off,
                                                      const int* __restrict__ csr_src, const float* __restrict__ dinv,
                                                      const float* __restrict__ bias, _Float16* __restrict__ out16, int n){
  int node = blockIdx.x * 4 + (threadIdx.x >> 6);
  if (node >= n) return;
  int lane = threadIdx.x & 63;
  int e = row_off[node], eend = row_off[node + 1];
  float di = dinv[node];
  half2v sv = *reinterpret_cast<const half2v*>(h16 + (size_t)node * 128 + lane * 2);
  float ax = (float)sv[0], ay = (float)sv[1];
  while (e < eend){
    int m = eend - e; if (m > 64) m = 64;
    int idx = (lane < m) ? __builtin_nontemporal_load(csr_src + e + lane) : 0;
    int i = 0;
    for (; i + 16 <= m; i += 16){
      half2v v[16];
      #pragma unroll
      for (int j = 0; j < 16; j++){
        int s = __shfl(idx, i + j);
        v[j] = *reinterpret_cast<const half2v*>(h16 + (size_t)s * 128 + lane * 2);
      }
      #pragma unroll
      for (int j = 0; j < 16; j++){ ax += (float)v[j][0]; ay += (float)v[j][1]; }
    }
    for (; i + 4 <= m; i += 4){
      half2v v[4];
      #pragma unroll
      for (int j = 0; j < 4; j++){
        int s = __shfl(idx, i + j);
        v[j] = *reinterpret_cast<const half2v*>(h16 + (size_t)s * 128 + lane * 2);
      }
      #pragma unroll
      for (int j = 0; j < 4; j++){ ax += (float)v[j][0]; ay += (float)v[j][1]; }
    }
    for (; i < m; i++){
      int s = __shfl(idx, i);
      half2v v = *reinterpret_cast<const half2v*>(h16 + (size_t)s * 128 + lane * 2);
      ax += (float)v[0]; ay += (float)v[1];
    }
    e += m;
  }
  float2 bv = *reinterpret_cast<const float2*>(bias + lane * 2);
  float ox = fmaxf(fmaf(di, ax, bv.x), 0.f);
  float oy = fmaxf(fmaf(di, ay, bv.y), 0.f);
  half2v o; o[0] = (_Float16)ox; o[1] = (_Float16)oy;
  *reinterpret_cast<half2v*>(out16 + (size_t)node * 128 + lane * 2) = o;
}

// layer-3 agg (64-dim, h' pre-scaled) with fused classifier

__global__ __launch_bounds__(256) void agg64h_cls_kernel(const _Float16* __restrict__ h16, const int* __restrict__ row_off,
                                                         const int* __restrict__ csr_src, const float* __restrict__ dinv,
                                                         const float* __restrict__ bias, const float* __restrict__ Wc,
                                                         const float* __restrict__ bc, float* __restrict__ out, int n){
  int node = blockIdx.x * 4 + (threadIdx.x >> 6);
  if (node >= n) return;
  int lane = threadIdx.x & 63;
  int e = row_off[node], eend = row_off[node + 1];
  float di = dinv[node];
  float a = (float)h16[(size_t)node * 64 + lane];
  while (e < eend){
    int m = eend - e; if (m > 64) m = 64;
    int idx = (lane < m) ? __builtin_nontemporal_load(csr_src + e + lane) : 0;
    int i = 0;
    for (; i + 16 <= m; i += 16){
      _Float16 v[16];
      #pragma unroll
      for (int j = 0; j < 16; j++){
        int s = __shfl(idx, i + j);
        v[j] = h16[(size_t)s * 64 + lane];
      }
      #pragma unroll
      for (int j = 0; j < 16; j++) a += (float)v[j];
    }
    for (; i + 4 <= m; i += 4){
      _Float16 v[4];
      #pragma unroll
      for (int j = 0; j < 4; j++){
        int s = __shfl(idx, i + j);
        v[j] = h16[(size_t)s * 64 + lane];
      }
      #pragma unroll
      for (int j = 0; j < 4; j++) a += (float)v[j];
    }
    for (; i < m; i++){
      int s = __shfl(idx, i);
      a += (float)h16[(size_t)s * 64 + lane];
    }
    e += m;
  }
  float o = fmaxf(fmaf(di, a, bias[lane]), 0.f);
  float v = o * Wc[lane];
  #pragma unroll
  for (int off = 32; off > 0; off >>= 1) v += __shfl_down(v, off);
  if (lane == 0) out[node] = v + bc[0];
}

// ---------------- launch ----------------

extern "C" void kernel_launch(void* const* d_in, const int* in_sizes, int n_in,
                              void* d_out, int out_size, void* d_ws, size_t ws_size,
                              hipStream_t stream){
  const float* x  = (const float*)d_in[0];
  const int*   ei = (const int*)d_in[1];
  const float* W1 = (const float*)d_in[2];
  const float* b1 = (const float*)d_in[3];
  const float* W2 = (const float*)d_in[4];
  const float* b2 = (const float*)d_in[5];
  const float* W3 = (const float*)d_in[6];
  const float* b3 = (const float*)d_in[7];
  const float* Wc = (const float*)d_in[8];
  const float* bc = (const float*)d_in[9];
  float* out = (float*)d_out;

  int N = in_sizes[0] / 256;
  int E = in_sizes[1] / 2;
  const int* src = ei;
  const int* dst = ei + E;
  int NBK = (N + (1 << BSH) - 1) >> BSH;   // 196 for N=100000

  char* ws = (char*)d_ws;
  size_t off = 0;
  auto alloc = [&](size_t bytes) -> char* {
    char* p = ws + off;
    off += (bytes + 511) & ~(size_t)511;
    return p;
  };
  int*      bktcnt  = (int*)     alloc((size_t)NBK * 4);
  int*      bbase   = (int*)     alloc(((size_t)NBK + 1) * 4);
  int*      bcur    = (int*)     alloc((size_t)NBK * 4);
  float*    dinv    = (float*)   alloc((size_t)N * 4);
  int*      row_off = (int*)     alloc(((size_t)N + 1) * 4);
  unsigned* tmp     = (unsigned*)alloc((size_t)E * 4);
  int*      csr_src = (int*)     alloc((size_t)E * 4);
  _Float16* bufH    = (_Float16*)alloc((size_t)N * 128 * 2);  // gemm outputs (dinv-scaled)
  _Float16* bufG    = (_Float16*)alloc((size_t)N * 128 * 2);  // agg outputs (fp16)
  _Float16* W1t     = (_Float16*)alloc((size_t)256 * 128 * 2);
  _Float16* W2t     = (_Float16*)alloc((size_t)128 * 128 * 2);
  _Float16* W3t     = (_Float16*)alloc((size_t)128 * 64 * 2);

  // K1: wcvt || bucket histogram
  hipMemsetAsync(bktcnt, 0, (size_t)NBK * 4, stream);
  wcvt_bhist_kernel<<<224 + cdiv(E, HCH), 256, 0, stream>>>(W1, W1t, W2, W2t, W3, W3t, dst, bktcnt, E, NBK);
  // K2: bucket scan
  bucket_scan_kernel<<<1, 256, 0, stream>>>(bktcnt, bbase, bcur, NBK, E);
  // K3: bucket scatter
  bucket_scatter_kernel<<<cdiv(E, CH), 256, 0, stream>>>(src, dst, bcur, tmp, E, NBK);
  // K4: per-bucket build (row_off + dinv + csr_src)
  bucket_build_kernel<<<NBK, 256, 0, stream>>>(tmp, bbase, row_off, dinv, csr_src, N, E, NBK);
  // layer 1: bufH = dinv*(x@W1) fp16; agg -> bufG
  mgemm_kernel<128, true ><<<cdiv(N, 128), 256, 0, stream>>>(x, W1t, bufH, dinv, N, 256);
  agg128h_kernel<<<cdiv(N, 4), 256, 0, stream>>>(bufH, row_off, csr_src, dinv, b1, bufG, N);
  // layer 2
  mgemm_kernel<128, false><<<cdiv(N, 128), 256, 0, stream>>>(bufG, W2t, bufH, dinv, N, 128);
  agg128h_kernel<<<cdiv(N, 4), 256, 0, stream>>>(bufH, row_off, csr_src, dinv, b2, bufG, N);
  // layer 3 (128 -> 64) + fused classifier
  mgemm_kernel<64, false><<<cdiv(N, 128), 256, 0, stream>>>(bufG, W3t, bufH, dinv, N, 128);
  agg64h_cls_kernel<<<cdiv(N, 4), 256, 0, stream>>>(bufH, row_off, csr_src, dinv, b3, Wc, bc, out, N);
}

// Round 14
// 296.518 us; speedup vs baseline: 1.3272x; 1.0484x over previous
//
#include <hip/hip_runtime.h>
#include <cstdint>
#include <cstddef>

typedef __attribute__((ext_vector_type(4))) float f32x4;
typedef __attribute__((ext_vector_type(8))) _Float16 half8v;
typedef __attribute__((ext_vector_type(2))) _Float16 half2v;

static inline int cdiv(int a, int b){ return (a + b - 1) / b; }

#define BSH 9              // bucket shift: 512 nodes per bucket
#define CH 8192            // edges per scatter block
#define HCH 8192           // edges per histogram block

// ---------------- K1: weight-convert (blocks 0..223) || bucket histogram (rest) ----------------

__global__ __launch_bounds__(256) void wcvt_bhist_kernel(const float* __restrict__ W1, _Float16* __restrict__ W1t,
                                                         const float* __restrict__ W2, _Float16* __restrict__ W2t,
                                                         const float* __restrict__ W3, _Float16* __restrict__ W3t,
                                                         const int* __restrict__ dst, int* __restrict__ bktcnt,
                                                         int E, int NBK){
  __shared__ int hist[1024];
  int b = blockIdx.x, t = threadIdx.x;
  if (b < 224){
    int i = b * 256 + t;
    if (b < 128){
      int k = i / 128, n = i & 127;
      W1t[(size_t)n * 256 + k] = (_Float16)W1[i];
    } else if (b < 192){
      int j = i - 128 * 256;
      int k = j / 128, n = j & 127;
      W2t[(size_t)n * 128 + k] = (_Float16)W2[j];
    } else {
      int j = i - 192 * 256;
      int k = j / 64, n = j & 63;
      W3t[(size_t)n * 128 + k] = (_Float16)W3[j];
    }
    return;
  }
  int cb = b - 224;
  for (int i = t; i < NBK; i += 256) hist[i] = 0;
  __syncthreads();
  int e0 = cb * HCH;
  int e1 = e0 + HCH; if (e1 > E) e1 = E;
  for (int i = e0 + t; i < e1; i += 256){
    int d = __builtin_nontemporal_load(dst + i);
    atomicAdd(&hist[d >> BSH], 1);
  }
  __syncthreads();
  for (int i = t; i < NBK; i += 256){
    int h = hist[i];
    if (h) atomicAdd(&bktcnt[i], h);
  }
}

// ---------------- K2: one-block scan over NBK bucket counts -> bbase, bcur ----------------

__global__ __launch_bounds__(256) void bucket_scan_kernel(const int* __restrict__ bktcnt, int* __restrict__ bbase,
                                                          int* __restrict__ bcur, int NBK, int E){
  __shared__ int sdata[256];
  int t = threadIdx.x;
  int c = (t < NBK) ? bktcnt[t] : 0;
  sdata[t] = c;
  __syncthreads();
  for (int off = 1; off < 256; off <<= 1){
    int v = (t >= off) ? sdata[t - off] : 0;
    __syncthreads();
    sdata[t] += v;
    __syncthreads();
  }
  if (t < NBK){
    int ex = sdata[t] - c;
    bbase[t] = ex;
    bcur[t] = ex;
  }
  if (t == 0) bbase[NBK] = E;
}

// ---------------- K3: block-histogram bucket scatter ----------------

__global__ __launch_bounds__(256) void bucket_scatter_kernel(const int* __restrict__ src, const int* __restrict__ dst,
                                                             int* __restrict__ bcur, unsigned* __restrict__ tmp,
                                                             int E, int NBK){
  __shared__ int hist[1024];
  __shared__ int hbase[1024];
  __shared__ unsigned pk[CH];
  __shared__ unsigned short bkt[CH];
  int t = threadIdx.x;
  int e0 = blockIdx.x * CH;
  int e1 = e0 + CH; if (e1 > E) e1 = E;
  int nloc = e1 - e0;
  for (int i = t; i < NBK; i += 256) hist[i] = 0;
  __syncthreads();
  for (int i = t; i < nloc; i += 256){
    int d = __builtin_nontemporal_load(dst + e0 + i);
    int s = __builtin_nontemporal_load(src + e0 + i);
    int b = d >> BSH;
    pk[i]  = ((unsigned)s << BSH) | (unsigned)(d & ((1 << BSH) - 1));
    bkt[i] = (unsigned short)b;
    atomicAdd(&hist[b], 1);
  }
  __syncthreads();
  for (int i = t; i < NBK; i += 256){
    int h = hist[i];
    hbase[i] = h ? atomicAdd(&bcur[i], h) : 0;
    hist[i] = 0;                         // reuse as intra-block cursor
  }
  __syncthreads();
  for (int i = t; i < nloc; i += 256){
    int b = bkt[i];
    int pos = atomicAdd(&hist[b], 1);
    tmp[hbase[b] + pos] = pk[i];
  }
}

// ---------------- K4: per-bucket build: node histogram -> dinv + row_off (LDS scan) -> cursor sort ----------------

__global__ __launch_bounds__(256) void bucket_build_kernel(const unsigned* __restrict__ tmp, const int* __restrict__ bbase,
                                                           int* __restrict__ row_off, float* __restrict__ dinv,
                                                           int* __restrict__ csr_src, int N, int E, int NBK){
  __shared__ int hist[512];
  __shared__ int sdata[256];
  __shared__ int lofs[512];
  int g = blockIdx.x;
  int base = g << BSH;
  int nloc = N - base; if (nloc > 512) nloc = 512;
  int t = threadIdx.x;
  int rs = bbase[g], re = bbase[g + 1];
  hist[t] = 0; hist[t + 256] = 0;
  __syncthreads();
  for (int i = rs + t; i < re; i += 256)
    atomicAdd(&hist[tmp[i] & 511], 1);
  __syncthreads();
  int h0 = hist[2 * t], h1 = hist[2 * t + 1];
  int pairsum = h0 + h1;
  sdata[t] = pairsum;
  __syncthreads();
  for (int off = 1; off < 256; off <<= 1){
    int v = (t >= off) ? sdata[t - off] : 0;
    __syncthreads();
    sdata[t] += v;
    __syncthreads();
  }
  int ex = sdata[t] - pairsum;
  lofs[2 * t] = ex;
  lofs[2 * t + 1] = ex + h0;
  __syncthreads();
  for (int j = t; j < nloc; j += 256){
    dinv[base + j] = rsqrtf((float)hist[j] + 1.0f);
    row_off[base + j] = rs + lofs[j];
  }
  if (g == NBK - 1 && t == 0) row_off[N] = E;
  __syncthreads();
  for (int j = t; j < 512; j += 256) hist[j] = rs + lofs[j];   // reuse as cursors
  __syncthreads();
  for (int i = rs + t; i < re; i += 256){
    unsigned v = tmp[i];
    int slot = atomicAdd(&hist[v & 511], 1);
    csr_src[slot] = (int)(v >> BSH);
  }
}

// ---------------- pipelined MFMA GEMM: C16[row] = fp16(dscale[row] * (A @ Bt^T)[row]) ----------------
// BM=64 (grid 1563 blocks -> ~6 blocks/CU: TLP hides HBM latency; BM=128 capped at 3 blocks/CU
// and 20% occupancy), BK=32, 4 waves x (32-row x 64/32-col) sub-tiles, 2-stage reg prefetch.
//   A: lane l row (l&15), k = 8*(l>>4)+{0..7}; B: lane l col (l&15), same k
//   D: lane l reg r -> row = 4*(l>>4)+r, col = (l&15)

template<int BN, bool A32IN>
__global__ __launch_bounds__(256) void mgemm_kernel(const void* __restrict__ Ain, const _Float16* __restrict__ Bt,
                                                    _Float16* __restrict__ C16, const float* __restrict__ dscale,
                                                    int M, int K){
  constexpr int BM = 64, LD = 40;    // stride 40 halves: 16B-aligned rows, <=2-way bank aliasing
  constexpr int MF = 2;
  constexpr int NF = (BN == 128) ? 4 : 2;
  constexpr int NBC = (BN * 4) / 256;   // B chunks per thread (2 for BN=128, 1 for BN=64)
  __shared__ _Float16 As[BM * LD];
  __shared__ _Float16 Bs[BN * LD];
  const float*    A32 = (const float*)Ain;
  const _Float16* A16 = (const _Float16*)Ain;
  int t = threadIdx.x;
  int w = t >> 6, l = t & 63;
  int m0 = blockIdx.x * BM;
  int wm = (w >> 1) * 32;
  int wn = (w & 1) * ((BN == 128) ? 64 : 32);
  int lr = l & 15;
  int kg = (l >> 4) * 8;

  int arow = t >> 2, ac = t & 3;       // one A chunk per thread (64 rows x 4 chunks)
  int ag = m0 + arow;

  f32x4 acc[MF][NF];
  #pragma unroll
  for (int i = 0; i < MF; i++)
    #pragma unroll
    for (int j = 0; j < NF; j++){
      f32x4 z = {0.f, 0.f, 0.f, 0.f};
      acc[i][j] = z;
    }

  float4 ar0[2];          // A32 path
  half8v ar16;            // A16 path
  half8v br[NBC];

  auto loadA = [&](int k0){
    if (A32IN){
      if (ag < M){
        const float* ap = A32 + (size_t)ag * K + k0 + ac * 8;
        ar0[0] = *reinterpret_cast<const float4*>(ap);
        ar0[1] = *reinterpret_cast<const float4*>(ap + 4);
      } else {
        ar0[0] = make_float4(0.f, 0.f, 0.f, 0.f);
        ar0[1] = make_float4(0.f, 0.f, 0.f, 0.f);
      }
    } else {
      if (ag < M){
        ar16 = *reinterpret_cast<const half8v*>(A16 + (size_t)ag * K + k0 + ac * 8);
      } else {
        half8v z = {(_Float16)0, (_Float16)0, (_Float16)0, (_Float16)0,
                    (_Float16)0, (_Float16)0, (_Float16)0, (_Float16)0};
        ar16 = z;
      }
    }
  };
  auto loadB = [&](int k0){
    #pragma unroll
    for (int j = 0; j < NBC; j++){
      int i = t + j * 256;
      int row = i >> 2, c = i & 3;
      br[j] = *reinterpret_cast<const half8v*>(Bt + (size_t)row * K + k0 + c * 8);
    }
  };
  auto storeLDS = [&](){
    half8v hv;
    if (A32IN){
      hv[0] = (_Float16)ar0[0].x; hv[1] = (_Float16)ar0[0].y;
      hv[2] = (_Float16)ar0[0].z; hv[3] = (_Float16)ar0[0].w;
      hv[4] = (_Float16)ar0[1].x; hv[5] = (_Float16)ar0[1].y;
      hv[6] = (_Float16)ar0[1].z; hv[7] = (_Float16)ar0[1].w;
    } else {
      hv = ar16;
    }
    *reinterpret_cast<half8v*>(&As[arow * LD + ac * 8]) = hv;
    #pragma unroll
    for (int j = 0; j < NBC; j++){
      int i = t + j * 256;
      int row = i >> 2, c = i & 3;
      *reinterpret_cast<half8v*>(&Bs[row * LD + c * 8]) = br[j];
    }
  };

  loadA(0); loadB(0);
  for (int k0 = 0; k0 < K; k0 += 32){
    storeLDS();                        // implicit vmcnt wait on staged loads
    __syncthreads();
    if (k0 + 32 < K){ loadA(k0 + 32); loadB(k0 + 32); }   // issue next tile early
    half8v af[MF];
    #pragma unroll
    for (int mf = 0; mf < MF; mf++)
      af[mf] = *reinterpret_cast<const half8v*>(&As[(wm + mf * 16 + lr) * LD + kg]);
    #pragma unroll
    for (int nf = 0; nf < NF; nf++){
      half8v bf = *reinterpret_cast<const half8v*>(&Bs[(wn + nf * 16 + lr) * LD + kg]);
      #pragma unroll
      for (int mf = 0; mf < MF; mf++)
        acc[mf][nf] = __builtin_amdgcn_mfma_f32_16x16x32_f16(af[mf], bf, acc[mf][nf], 0, 0, 0);
    }
    __syncthreads();                   // LDS consumed; next storeLDS may overwrite
  }
  #pragma unroll
  for (int mf = 0; mf < MF; mf++){
    #pragma unroll
    for (int r = 0; r < 4; r++){
      int row = m0 + wm + mf * 16 + (l >> 4) * 4 + r;
      if (row < M){
        float sc = dscale[row];
        #pragma unroll
        for (int nf = 0; nf < NF; nf++)
          C16[(size_t)row * BN + wn + nf * 16 + lr] = (_Float16)(sc * acc[mf][nf][r]);
      }
    }
  }
}

// ---------------- aggregation: out = relu(di * (sum_{s in N(i)} h'_s + h'_i) + b) ----------------
// h' is already dinv-scaled (GEMM epilogue). One node per wave (proven-fast shape, round 9-11).

__global__ __launch_bounds__(256) void agg128h_kernel(const _Float16* __restrict__ h16, const int* __restrict__ row_off,
                                                      const int* __restrict__ csr_src, const float* __restrict__ dinv,
                                                      const float* __restrict__ bias, _Float16* __restrict__ out16, int n){
  int node = blockIdx.x * 4 + (threadIdx.x >> 6);
  if (node >= n) return;
  int lane = threadIdx.x & 63;
  int e = row_off[node], eend = row_off[node + 1];
  float di = dinv[node];
  half2v sv = *reinterpret_cast<const half2v*>(h16 + (size_t)node * 128 + lane * 2);
  float ax = (float)sv[0], ay = (float)sv[1];
  while (e < eend){
    int m = eend - e; if (m > 64) m = 64;
    int idx = (lane < m) ? csr_src[e + lane] : 0;
    int i = 0;
    for (; i + 16 <= m; i += 16){
      half2v v[16];
      #pragma unroll
      for (int j = 0; j < 16; j++){
        int s = __shfl(idx, i + j);
        v[j] = *reinterpret_cast<const half2v*>(h16 + (size_t)s * 128 + lane * 2);
      }
      #pragma unroll
      for (int j = 0; j < 16; j++){ ax += (float)v[j][0]; ay += (float)v[j][1]; }
    }
    for (; i + 4 <= m; i += 4){
      half2v v[4];
      #pragma unroll
      for (int j = 0; j < 4; j++){
        int s = __shfl(idx, i + j);
        v[j] = *reinterpret_cast<const half2v*>(h16 + (size_t)s * 128 + lane * 2);
      }
      #pragma unroll
      for (int j = 0; j < 4; j++){ ax += (float)v[j][0]; ay += (float)v[j][1]; }
    }
    for (; i < m; i++){
      int s = __shfl(idx, i);
      half2v v = *reinterpret_cast<const half2v*>(h16 + (size_t)s * 128 + lane * 2);
      ax += (float)v[0]; ay += (float)v[1];
    }
    e += m;
  }
  float2 bv = *reinterpret_cast<const float2*>(bias + lane * 2);
  float ox = fmaxf(fmaf(di, ax, bv.x), 0.f);
  float oy = fmaxf(fmaf(di, ay, bv.y), 0.f);
  half2v o; o[0] = (_Float16)ox; o[1] = (_Float16)oy;
  *reinterpret_cast<half2v*>(out16 + (size_t)node * 128 + lane * 2) = o;
}

// layer-3 agg (64-dim, h' pre-scaled) with fused classifier

__global__ __launch_bounds__(256) void agg64h_cls_kernel(const _Float16* __restrict__ h16, const int* __restrict__ row_off,
                                                         const int* __restrict__ csr_src, const float* __restrict__ dinv,
                                                         const float* __restrict__ bias, const float* __restrict__ Wc,
                                                         const float* __restrict__ bc, float* __restrict__ out, int n){
  int node = blockIdx.x * 4 + (threadIdx.x >> 6);
  if (node >= n) return;
  int lane = threadIdx.x & 63;
  int e = row_off[node], eend = row_off[node + 1];
  float di = dinv[node];
  float a = (float)h16[(size_t)node * 64 + lane];
  while (e < eend){
    int m = eend - e; if (m > 64) m = 64;
    int idx = (lane < m) ? csr_src[e + lane] : 0;
    int i = 0;
    for (; i + 16 <= m; i += 16){
      _Float16 v[16];
      #pragma unroll
      for (int j = 0; j < 16; j++){
        int s = __shfl(idx, i + j);
        v[j] = h16[(size_t)s * 64 + lane];
      }
      #pragma unroll
      for (int j = 0; j < 16; j++) a += (float)v[j];
    }
    for (; i + 4 <= m; i += 4){
      _Float16 v[4];
      #pragma unroll
      for (int j = 0; j < 4; j++){
        int s = __shfl(idx, i + j);
        v[j] = h16[(size_t)s * 64 + lane];
      }
      #pragma unroll
      for (int j = 0; j < 4; j++) a += (float)v[j];
    }
    for (; i < m; i++){
      int s = __shfl(idx, i);
      a += (float)h16[(size_t)s * 64 + lane];
    }
    e += m;
  }
  float o = fmaxf(fmaf(di, a, bias[lane]), 0.f);
  float v = o * Wc[lane];
  #pragma unroll
  for (int off = 32; off > 0; off >>= 1) v += __shfl_down(v, off);
  if (lane == 0) out[node] = v + bc[0];
}

// ---------------- launch ----------------

extern "C" void kernel_launch(void* const* d_in, const int* in_sizes, int n_in,
                              void* d_out, int out_size, void* d_ws, size_t ws_size,
                              hipStream_t stream){
  const float* x  = (const float*)d_in[0];
  const int*   ei = (const int*)d_in[1];
  const float* W1 = (const float*)d_in[2];
  const float* b1 = (const float*)d_in[3];
  const float* W2 = (const float*)d_in[4];
  const float* b2 = (const float*)d_in[5];
  const float* W3 = (const float*)d_in[6];
  const float* b3 = (const float*)d_in[7];
  const float* Wc = (const float*)d_in[8];
  const float* bc = (const float*)d_in[9];
  float* out = (float*)d_out;

  int N = in_sizes[0] / 256;
  int E = in_sizes[1] / 2;
  const int* src = ei;
  const int* dst = ei + E;
  int NBK = (N + (1 << BSH) - 1) >> BSH;   // 196 for N=100000

  char* ws = (char*)d_ws;
  size_t off = 0;
  auto alloc = [&](size_t bytes) -> char* {
    char* p = ws + off;
    off += (bytes + 511) & ~(size_t)511;
    return p;
  };
  int*      bktcnt  = (int*)     alloc((size_t)NBK * 4);
  int*      bbase   = (int*)     alloc(((size_t)NBK + 1) * 4);
  int*      bcur    = (int*)     alloc((size_t)NBK * 4);
  float*    dinv    = (float*)   alloc((size_t)N * 4);
  int*      row_off = (int*)     alloc(((size_t)N + 1) * 4);
  unsigned* tmp     = (unsigned*)alloc((size_t)E * 4);
  int*      csr_src = (int*)     alloc((size_t)E * 4);
  _Float16* bufH    = (_Float16*)alloc((size_t)N * 128 * 2);  // gemm outputs (dinv-scaled)
  _Float16* bufG    = (_Float16*)alloc((size_t)N * 128 * 2);  // agg outputs (fp16)
  _Float16* W1t     = (_Float16*)alloc((size_t)256 * 128 * 2);
  _Float16* W2t     = (_Float16*)alloc((size_t)128 * 128 * 2);
  _Float16* W3t     = (_Float16*)alloc((size_t)128 * 64 * 2);

  // K1: wcvt || bucket histogram
  hipMemsetAsync(bktcnt, 0, (size_t)NBK * 4, stream);
  wcvt_bhist_kernel<<<224 + cdiv(E, HCH), 256, 0, stream>>>(W1, W1t, W2, W2t, W3, W3t, dst, bktcnt, E, NBK);
  // K2: bucket scan
  bucket_scan_kernel<<<1, 256, 0, stream>>>(bktcnt, bbase, bcur, NBK, E);
  // K3: bucket scatter
  bucket_scatter_kernel<<<cdiv(E, CH), 256, 0, stream>>>(src, dst, bcur, tmp, E, NBK);
  // K4: per-bucket build (row_off + dinv + csr_src)
  bucket_build_kernel<<<NBK, 256, 0, stream>>>(tmp, bbase, row_off, dinv, csr_src, N, E, NBK);
  // layer 1: bufH = dinv*(x@W1) fp16; agg -> bufG
  mgemm_kernel<128, true ><<<cdiv(N, 64), 256, 0, stream>>>(x, W1t, bufH, dinv, N, 256);
  agg128h_kernel<<<cdiv(N, 4), 256, 0, stream>>>(bufH, row_off, csr_src, dinv, b1, bufG, N);
  // layer 2
  mgemm_kernel<128, false><<<cdiv(N, 64), 256, 0, stream>>>(bufG, W2t, bufH, dinv, N, 128);
  agg128h_kernel<<<cdiv(N, 4), 256, 0, stream>>>(bufH, row_off, csr_src, dinv, b2, bufG, N);
  // layer 3 (128 -> 64) + fused classifier
  mgemm_kernel<64, false><<<cdiv(N, 64), 256, 0, stream>>>(bufG, W3t, bufH, dinv, N, 128);
  agg64h_cls_kernel<<<cdiv(N, 4), 256, 0, stream>>>(bufH, row_off, csr_src, dinv, b3, Wc, bc, out, N);
}